// Round 10
// baseline (114.569 us; speedup 1.0000x reference)
//
#include <hip/hip_runtime.h>
#include <math.h>

#define B_SZ 8192
#define HID 256
#define DIM 128
#define MAXN 64
#define KM 160     // key_net mid
#define DM 192     // decoder mid
#define SM 128     // size_pred mid
#define LN_EPS 1e-5f

#define NB 32                  // batches per block
#define GRID_BLKS (B_SZ / NB)  // 256
#define ZPAD 36                // z_s row stride (dwords)

// Single-kernel design: each block owns 32 batches end-to-end.
// sizepred GEMM -> fill rows j>=n -> compute needed keys rows (nmax ~ 2-3) -> decode rows j<n.
// No workspace, no atomics, no cross-block dependencies, ONE graph node.
__global__ void __launch_bounds__(256) uber_kernel(
    const float* __restrict__ z,
    const float* __restrict__ kW1, const float* __restrict__ kb1,
    const float* __restrict__ kg,  const float* __restrict__ kbe,
    const float* __restrict__ kW2, const float* __restrict__ kb2,
    const float* __restrict__ sW1, const float* __restrict__ sb1,
    const float* __restrict__ sg,  const float* __restrict__ sbe,
    const float* __restrict__ sW2, const float* __restrict__ sb2,
    const float* __restrict__ dW1, const float* __restrict__ db1,
    const float* __restrict__ dW2, const float* __restrict__ db2,
    float* __restrict__ out0, float* __restrict__ out_logits,
    float* __restrict__ out_nf)
{
    __shared__ __align__(16) float z_s[HID][ZPAD];       // 36 KB, z_s[k][b] transposed
    __shared__ __align__(16) float keys_s[MAXN][HID];    // 64 KB (worst case; ~3 rows used)
    __shared__ __align__(16) float s_s[HID][4];          // 4 KB
    __shared__ __align__(16) float t_s[DM][4];           // 3 KB (also keys t_k scratch)
    __shared__ __align__(16) float pbuf[4 * DM * 4];     // 12 KB (hp/op; also red scratch)
    __shared__ int n_s[NB];                              // 128 B
    __shared__ unsigned short rlist[NB * (MAXN - 1)];    // 4032 B

    const int blk = blockIdx.x;
    const int tid = threadIdx.x;
    const int w = tid >> 6, lane = tid & 63;
    const int b0 = blk * NB;

    // ================= Phase A: stage z transposed =================
    {
        const float4* z4 = (const float4*)z;
        #pragma unroll
        for (int i = 0; i < 8; ++i) {
            const int idx = tid + 256 * i;
            const int r = idx >> 6, c4 = idx & 63;
            const float4 v = z4[(size_t)(b0 + r) * 64 + c4];
            z_s[4 * c4 + 0][r] = v.x;
            z_s[4 * c4 + 1][r] = v.y;
            z_s[4 * c4 + 2][r] = v.z;
            z_s[4 * c4 + 3][r] = v.w;
        }
    }
    __syncthreads();

    // ================= Phase B: sizepred GEMM (verified R3 tile) =================
    {
        const int cq = tid & 31;   // col quad: cols 4cq..4cq+3
        const int bg = tid >> 5;   // batch group: batches 4bg..4bg+3

        float acc[4][4];
        #pragma unroll
        for (int bi = 0; bi < 4; ++bi)
            #pragma unroll
            for (int ci = 0; ci < 4; ++ci) acc[bi][ci] = 0.f;

        const float4* w4p = (const float4*)sW1;
        #pragma unroll 4
        for (int k = 0; k < HID; ++k) {
            const float4 wv = w4p[k * 32 + cq];
            const float4 zb = *(const float4*)&z_s[k][bg * 4];
            const float zz[4] = {zb.x, zb.y, zb.z, zb.w};
            const float ww[4] = {wv.x, wv.y, wv.z, wv.w};
            #pragma unroll
            for (int bi = 0; bi < 4; ++bi)
                #pragma unroll
                for (int ci = 0; ci < 4; ++ci)
                    acc[bi][ci] = fmaf(zz[bi], ww[ci], acc[bi][ci]);
        }

        const float4 g4v  = ((const float4*)sg)[cq];
        const float4 be4v = ((const float4*)sbe)[cq];
        const float4 w24v = ((const float4*)sW2)[cq];
        const float g4[4]  = {g4v.x, g4v.y, g4v.z, g4v.w};
        const float be4[4] = {be4v.x, be4v.y, be4v.z, be4v.w};
        const float w24[4] = {w24v.x, w24v.y, w24v.z, w24v.w};
        const float sb2v = sb2[0];
        const float b1_0 = sb1[4 * cq + 0], b1_1 = sb1[4 * cq + 1],
                    b1_2 = sb1[4 * cq + 2], b1_3 = sb1[4 * cq + 3];

        #pragma unroll
        for (int bi = 0; bi < 4; ++bi) {
            float a[4] = {acc[bi][0] + b1_0, acc[bi][1] + b1_1,
                          acc[bi][2] + b1_2, acc[bi][3] + b1_3};
            float s = a[0] + a[1] + a[2] + a[3];
            #pragma unroll
            for (int off = 1; off < 32; off <<= 1) s += __shfl_xor(s, off, 64);
            const float mu = s * (1.f / (float)SM);
            float d[4], vs = 0.f;
            #pragma unroll
            for (int ci = 0; ci < 4; ++ci) { d[ci] = a[ci] - mu; vs = fmaf(d[ci], d[ci], vs); }
            #pragma unroll
            for (int off = 1; off < 32; off <<= 1) vs += __shfl_xor(vs, off, 64);
            const float rstd = rsqrtf(vs * (1.f / (float)SM) + LN_EPS);

            float p = 0.f;
            #pragma unroll
            for (int ci = 0; ci < 4; ++ci) {
                float h = fmaf(d[ci] * rstd, g4[ci], be4[ci]);
                h = fmaxf(h, 0.f);
                p = fmaf(h, w24[ci], p);
            }
            #pragma unroll
            for (int off = 1; off < 32; off <<= 1) p += __shfl_xor(p, off, 64);

            if (cq == 0) {
                const int bl = bg * 4 + bi;           // local batch index
                const float logit = p + sb2v;
                int n = (int)rintf(logit);            // round-half-even == jnp.round
                n = min(max(n, 0), MAXN - 1);
                out_logits[b0 + bl] = logit;
                out_nf[b0 + bl] = (float)n;
                n_s[bl] = n;
            }
        }
    }
    __syncthreads();

    // ================= Phase C: fill invalid rows j >= n (stores drain in background) ====
    {
        const float4 zf = make_float4(0.f, 0.f, 0.f, 0.f);
        for (int bi = 0; bi < NB; ++bi) {
            const int n = n_s[bi];
            float4* o4 = (float4*)(out0 + (size_t)(b0 + bi) * (MAXN * DIM)) + n * 32;
            const int cnt4 = (MAXN - n) * 32;
            for (int idx = tid; idx < cnt4; idx += 256) o4[idx] = zf;
        }
    }

    // ================= Phase D: totals + row list =================
    int total = 0, nmax = 0;
    for (int i = 0; i < NB; ++i) {
        const int nn = n_s[i];
        total += nn;
        nmax = max(nmax, nn);
    }
    if (total == 0) return;

    if (tid < NB) {
        int off = 0;
        for (int i = 0; i < tid; ++i) off += n_s[i];
        const int nn = n_s[tid];
        for (int j = 0; j < nn; ++j)
            rlist[off + j] = (unsigned short)((tid << 6) | j);
    }
    __syncthreads();

    // ================= Phase E: compute keys rows 0..nmax-1 into LDS =================
    {
        float* red = pbuf;           // 256-float scratch
        float* t_k = (float*)t_s;    // >=160-float scratch
        for (int j = 0; j < nmax; ++j) {
            float v = 0.f;
            if (tid < KM) v = kW1[j * KM + tid] + kb1[tid];

            red[tid] = (tid < KM) ? v : 0.f;
            __syncthreads();
            for (int s = 128; s > 0; s >>= 1) {
                if (tid < s) red[tid] += red[tid + s];
                __syncthreads();
            }
            const float mu = red[0] / (float)KM;
            __syncthreads();

            const float d = (tid < KM) ? (v - mu) : 0.f;
            red[tid] = d * d;
            __syncthreads();
            for (int s = 128; s > 0; s >>= 1) {
                if (tid < s) red[tid] += red[tid + s];
                __syncthreads();
            }
            const float rstd = rsqrtf(red[0] / (float)KM + LN_EPS);
            __syncthreads();

            if (tid < KM) t_k[tid] = tanhf(d * rstd * kg[tid] + kbe[tid]);
            __syncthreads();

            float acc = kb2[tid];
            #pragma unroll 4
            for (int k = 0; k < KM; ++k) acc = fmaf(t_k[k], kW2[k * HID + tid], acc);
            keys_s[j][tid] = acc;
            __syncthreads();   // protect red/t_k for next j
        }
    }

    // ================= Phase F: decode valid rows, 4 per tile (verified R4/R8 tile) ======
    float (*hp)[DM][4]  = (float(*)[DM][4])pbuf;    // GEMV1 partials
    float (*op)[DIM][4] = (float(*)[DIM][4])pbuf;   // GEMV2 partials (aliased)

    for (int base = 0; base < total; base += 4) {
        const int rcnt = min(4, total - base);
        int bs[4], js[4];
        #pragma unroll
        for (int r = 0; r < 4; ++r) {
            const int e = rlist[base + min(r, rcnt - 1)];
            bs[r] = e >> 6; js[r] = e & 63;
        }

        // stage s[k][r] = z[b_r][k] * keys[j_r][k]   (k == tid; both from LDS)
        #pragma unroll
        for (int r = 0; r < 4; ++r)
            s_s[tid][r] = z_s[tid][bs[r]] * keys_s[js[r]][tid];
        __syncthreads();

        // GEMV1: wave w covers k in [64w, 64w+64); lane<48 owns cols 4lane..4lane+3
        if (lane < 48) {
            float a[4][4];
            #pragma unroll
            for (int r = 0; r < 4; ++r)
                #pragma unroll
                for (int c = 0; c < 4; ++c) a[r][c] = 0.f;
            const int k0 = w * 64;
            #pragma unroll 8
            for (int kk = 0; kk < 64; ++kk) {
                const int k = k0 + kk;
                const float4 wv = ((const float4*)dW1)[(size_t)k * 48 + lane];
                const float4 sv = *(const float4*)&s_s[k][0];
                const float sr[4] = {sv.x, sv.y, sv.z, sv.w};
                const float wc[4] = {wv.x, wv.y, wv.z, wv.w};
                #pragma unroll
                for (int r = 0; r < 4; ++r)
                    #pragma unroll
                    for (int c = 0; c < 4; ++c)
                        a[r][c] = fmaf(sr[r], wc[c], a[r][c]);
            }
            #pragma unroll
            for (int c = 0; c < 4; ++c)
                *(float4*)&hp[w][4 * lane + c][0] =
                    make_float4(a[0][c], a[1][c], a[2][c], a[3][c]);
        }
        __syncthreads();

        if (tid < DM) {
            const float4 p0 = *(const float4*)&hp[0][tid][0];
            const float4 p1 = *(const float4*)&hp[1][tid][0];
            const float4 p2 = *(const float4*)&hp[2][tid][0];
            const float4 p3 = *(const float4*)&hp[3][tid][0];
            const float bb = db1[tid];
            *(float4*)&t_s[tid][0] = make_float4(
                tanhf(p0.x + p1.x + p2.x + p3.x + bb),
                tanhf(p0.y + p1.y + p2.y + p3.y + bb),
                tanhf(p0.z + p1.z + p2.z + p3.z + bb),
                tanhf(p0.w + p1.w + p2.w + p3.w + bb));
        }
        __syncthreads();   // hp reads done; safe to alias as op

        // GEMV2: wave w covers k in [48w, 48w+48); lane<32 owns cols 4lane..4lane+3
        if (lane < 32) {
            float o[4][4];
            #pragma unroll
            for (int r = 0; r < 4; ++r)
                #pragma unroll
                for (int c = 0; c < 4; ++c) o[r][c] = 0.f;
            const int k1 = w * 48;
            #pragma unroll 8
            for (int kk = 0; kk < 48; ++kk) {
                const int k = k1 + kk;
                const float4 wv = ((const float4*)dW2)[(size_t)k * 32 + lane];
                const float4 tv = *(const float4*)&t_s[k][0];
                const float tr[4] = {tv.x, tv.y, tv.z, tv.w};
                const float wc[4] = {wv.x, wv.y, wv.z, wv.w};
                #pragma unroll
                for (int r = 0; r < 4; ++r)
                    #pragma unroll
                    for (int c = 0; c < 4; ++c)
                        o[r][c] = fmaf(tr[r], wc[c], o[r][c]);
            }
            #pragma unroll
            for (int c = 0; c < 4; ++c)
                *(float4*)&op[w][4 * lane + c][0] =
                    make_float4(o[0][c], o[1][c], o[2][c], o[3][c]);
        }
        __syncthreads();

        if (tid < DIM) {
            const float4 q0 = *(const float4*)&op[0][tid][0];
            const float4 q1 = *(const float4*)&op[1][tid][0];
            const float4 q2 = *(const float4*)&op[2][tid][0];
            const float4 q3 = *(const float4*)&op[3][tid][0];
            const float bb = db2[tid];
            const float ov[4] = {q0.x + q1.x + q2.x + q3.x + bb,
                                 q0.y + q1.y + q2.y + q3.y + bb,
                                 q0.z + q1.z + q2.z + q3.z + bb,
                                 q0.w + q1.w + q2.w + q3.w + bb};
            #pragma unroll
            for (int r = 0; r < 4; ++r)
                if (r < rcnt)
                    out0[((size_t)(b0 + bs[r]) * MAXN + js[r]) * DIM + tid] = ov[r];
        }
        __syncthreads();   // protect s_s/t_s/op before next tile
    }
}

extern "C" void kernel_launch(void* const* d_in, const int* in_sizes, int n_in,
                              void* d_out, int out_size, void* d_ws, size_t ws_size,
                              hipStream_t stream)
{
    const float* z   = (const float*)d_in[0];
    const float* kW1 = (const float*)d_in[1];
    const float* kb1 = (const float*)d_in[2];
    const float* kg  = (const float*)d_in[3];
    const float* kbe = (const float*)d_in[4];
    const float* kW2 = (const float*)d_in[5];
    const float* kb2 = (const float*)d_in[6];
    const float* dW1 = (const float*)d_in[7];
    const float* db1 = (const float*)d_in[8];
    const float* dW2 = (const float*)d_in[9];
    const float* db2 = (const float*)d_in[10];
    const float* sW1 = (const float*)d_in[11];
    const float* sb1 = (const float*)d_in[12];
    const float* sg  = (const float*)d_in[13];
    const float* sbe = (const float*)d_in[14];
    const float* sW2 = (const float*)d_in[15];
    const float* sb2 = (const float*)d_in[16];

    float* out0       = (float*)d_out;                         // [B, 64, 128]
    float* out_logits = out0 + (size_t)B_SZ * MAXN * DIM;      // [B, 1]
    float* out_nf     = out_logits + B_SZ;                     // [B]

    uber_kernel<<<GRID_BLKS, 256, 0, stream>>>(
        z, kW1, kb1, kg, kbe, kW2, kb2,
        sW1, sb1, sg, sbe, sW2, sb2,
        dW1, db1, dW2, db2,
        out0, out_logits, out_nf);
}

// Round 11
// 109.891 us; speedup vs baseline: 1.0426x; 1.0426x over previous
//
#include <hip/hip_runtime.h>
#include <math.h>

#define B_SZ 8192
#define HID 256
#define DIM 128
#define MAXN 64
#define KM 160     // key_net mid
#define DM 192     // decoder mid
#define SM 128     // size_pred mid
#define LN_EPS 1e-5f

#define NBATCH 4                     // batches per block
#define GRID_BLKS (B_SZ / NBATCH)    // 2048
#define KW 8                         // keys window rows held in LDS

// ONE kernel, ONE graph node. Each block owns 4 batches end-to-end:
//   branchless fill of all 4x64 rows -> sizepred GEMM (sW1 once/block)
//   -> per-block keys rows (windowed) -> decode valid rows (overwrite).
// No workspace, no atomics, no cross-block deps. Store ordering via barriers.
__global__ void __launch_bounds__(256) uber_kernel(
    const float* __restrict__ z,
    const float* __restrict__ kW1, const float* __restrict__ kb1,
    const float* __restrict__ kg,  const float* __restrict__ kbe,
    const float* __restrict__ kW2, const float* __restrict__ kb2,
    const float* __restrict__ sW1, const float* __restrict__ sb1,
    const float* __restrict__ sg,  const float* __restrict__ sbe,
    const float* __restrict__ sW2, const float* __restrict__ sb2,
    const float* __restrict__ dW1, const float* __restrict__ db1,
    const float* __restrict__ dW2, const float* __restrict__ db2,
    float* __restrict__ out0, float* __restrict__ out_logits,
    float* __restrict__ out_nf)
{
    __shared__ __align__(16) float z_s[HID][NBATCH];     // 4 KB, z_s[k][bi]
    __shared__ __align__(16) float keys_s[KW][HID];      // 8 KB
    __shared__ __align__(16) float s_s[HID][4];          // 4 KB (aliased as H in sizepred)
    __shared__ __align__(16) float t_s[DM][4];           // 3 KB (aliased as t_k in keys)
    __shared__ __align__(16) float pbuf[4 * DM * 4];     // 12 KB (hp/op, Hp, red)
    __shared__ int n_s[NBATCH];
    __shared__ unsigned short rlist[NBATCH * 8];         // one window's rows (<=32)
    __shared__ int wtot_s;

    const int tid = threadIdx.x;
    const int w = tid >> 6, lane = tid & 63;
    const int b0 = blockIdx.x * NBATCH;

    // ---- Phase A: issue z loads, then branchless fill of ALL rows (bulk stores) ----
    const float4 zreg = ((const float4*)z)[(size_t)(b0 + (tid >> 6)) * 64 + (tid & 63)];
    {
        const float4 zf = make_float4(0.f, 0.f, 0.f, 0.f);
        float4* o4 = (float4*)(out0 + (size_t)b0 * (MAXN * DIM));   // 128 KB contiguous
        #pragma unroll
        for (int i = 0; i < 32; ++i) o4[i * 256 + tid] = zf;
    }
    {   // stage z transposed: z_s[k][bi]
        const int bi = tid >> 6, c4 = tid & 63;
        z_s[4 * c4 + 0][bi] = zreg.x;
        z_s[4 * c4 + 1][bi] = zreg.y;
        z_s[4 * c4 + 2][bi] = zreg.z;
        z_s[4 * c4 + 3][bi] = zreg.w;
    }
    __syncthreads();

    // ---- Phase B: sizepred GEMM over 4 batches; sW1 read exactly once per block ----
    {
        const int c = tid & 127;          // hidden col 0..127
        const int half = tid >> 7;        // k half: [128*half, 128*half+128)
        float a0 = 0.f, a1 = 0.f, a2 = 0.f, a3 = 0.f;
        const int kk0 = half * 128;
        #pragma unroll 8
        for (int kk = 0; kk < 128; ++kk) {
            const int k = kk0 + kk;
            const float wv = sW1[k * SM + c];
            const float4 zb = *(const float4*)&z_s[k][0];
            a0 = fmaf(zb.x, wv, a0);
            a1 = fmaf(zb.y, wv, a1);
            a2 = fmaf(zb.z, wv, a2);
            a3 = fmaf(zb.w, wv, a3);
        }
        float* Hp = pbuf;                 // [2][128][4]
        *(float4*)&Hp[(half * 128 + c) * 4] = make_float4(a0, a1, a2, a3);
    }
    __syncthreads();
    float* H = (float*)s_s;               // [128][4]: H[c][bi] = pre-LN + bias
    if (tid < 128) {
        const float4 h0 = *(const float4*)&pbuf[tid * 4];
        const float4 h1 = *(const float4*)&pbuf[(128 + tid) * 4];
        const float bb = sb1[tid];
        H[tid * 4 + 0] = h0.x + h1.x + bb;
        H[tid * 4 + 1] = h0.y + h1.y + bb;
        H[tid * 4 + 2] = h0.z + h1.z + bb;
        H[tid * 4 + 3] = h0.w + h1.w + bb;
    }
    __syncthreads();
    {   // LN + ReLU + head: wave w handles batch w; lane covers cols lane, lane+64
        const float a0 = H[lane * 4 + w];
        const float a1 = H[(64 + lane) * 4 + w];
        float sum = a0 + a1;
        #pragma unroll
        for (int off = 1; off < 64; off <<= 1) sum += __shfl_xor(sum, off, 64);
        const float mu = sum * (1.f / (float)SM);
        const float d0 = a0 - mu, d1 = a1 - mu;
        float vs = d0 * d0 + d1 * d1;
        #pragma unroll
        for (int off = 1; off < 64; off <<= 1) vs += __shfl_xor(vs, off, 64);
        const float rstd = rsqrtf(vs * (1.f / (float)SM) + LN_EPS);

        float h0 = d0 * rstd * sg[lane]      + sbe[lane];
        float h1 = d1 * rstd * sg[64 + lane] + sbe[64 + lane];
        h0 = fmaxf(h0, 0.f);
        h1 = fmaxf(h1, 0.f);

        float p = fmaf(h0, sW2[lane], h1 * sW2[64 + lane]);
        #pragma unroll
        for (int off = 1; off < 64; off <<= 1) p += __shfl_xor(p, off, 64);

        if (lane == 0) {
            const float logit = p + sb2[0];
            int n = (int)rintf(logit);        // round-half-even == jnp.round
            n = min(max(n, 0), MAXN - 1);
            out_logits[b0 + w] = logit;
            out_nf[b0 + w] = (float)n;
            n_s[w] = n;
        }
    }
    __syncthreads();

    // ---- Phase C: totals ----
    int total = 0, nmax = 0;
    #pragma unroll
    for (int i = 0; i < NBATCH; ++i) {
        const int nn = n_s[i];
        total += nn;
        nmax = max(nmax, nn);
    }
    if (total == 0) return;   // ~76% of blocks; their fill stores drain on exit

    float (*hp)[DM][4]  = (float(*)[DM][4])pbuf;
    float (*op)[DIM][4] = (float(*)[DIM][4])pbuf;

    // ---- Phase D: windows of KW key rows ----
    for (int jlo = 0; jlo < nmax; jlo += KW) {
        const int jend = min(jlo + KW, nmax);

        // compute keys rows jlo..jend-1 into keys_s (verified key-row code)
        {
            float* red = pbuf;            // 256-float scratch
            float* t_k = (float*)t_s;     // >=160-float scratch
            for (int j = jlo; j < jend; ++j) {
                float v = 0.f;
                if (tid < KM) v = kW1[j * KM + tid] + kb1[tid];

                red[tid] = (tid < KM) ? v : 0.f;
                __syncthreads();
                for (int s = 128; s > 0; s >>= 1) {
                    if (tid < s) red[tid] += red[tid + s];
                    __syncthreads();
                }
                const float mu = red[0] / (float)KM;
                __syncthreads();

                const float d = (tid < KM) ? (v - mu) : 0.f;
                red[tid] = d * d;
                __syncthreads();
                for (int s = 128; s > 0; s >>= 1) {
                    if (tid < s) red[tid] += red[tid + s];
                    __syncthreads();
                }
                const float rstd = rsqrtf(red[0] / (float)KM + LN_EPS);
                __syncthreads();

                if (tid < KM) t_k[tid] = tanhf(d * rstd * kg[tid] + kbe[tid]);
                __syncthreads();

                float acc = kb2[tid];
                #pragma unroll 4
                for (int k = 0; k < KM; ++k) acc = fmaf(t_k[k], kW2[k * HID + tid], acc);
                keys_s[j - jlo][tid] = acc;
                __syncthreads();          // protect red/t_k for next row
            }
        }

        // build this window's row list (tiny serial scan by one thread)
        if (tid == 0) {
            int cnt = 0;
            for (int bi = 0; bi < NBATCH; ++bi) {
                const int hi = min(n_s[bi], jend);
                for (int j = jlo; j < hi; ++j)
                    rlist[cnt++] = (unsigned short)((bi << 6) | j);
            }
            wtot_s = cnt;
        }
        __syncthreads();
        const int wtot = wtot_s;

        // decode tiles: 4 rows per iteration (verified R8 tile)
        for (int base = 0; base < wtot; base += 4) {
            const int rcnt = min(4, wtot - base);
            int bs[4], js[4];
            #pragma unroll
            for (int r = 0; r < 4; ++r) {
                const int e = rlist[base + min(r, rcnt - 1)];
                bs[r] = e >> 6; js[r] = e & 63;
            }

            // stage s[k][r] = z[b_r][k] * keys[j_r][k]  (k == tid; both in LDS)
            #pragma unroll
            for (int r = 0; r < 4; ++r)
                s_s[tid][r] = z_s[tid][bs[r]] * keys_s[js[r] - jlo][tid];
            __syncthreads();

            // GEMV1: wave w covers k in [64w, 64w+64); lane<48 owns cols 4lane..4lane+3
            if (lane < 48) {
                float a[4][4];
                #pragma unroll
                for (int r = 0; r < 4; ++r)
                    #pragma unroll
                    for (int c = 0; c < 4; ++c) a[r][c] = 0.f;
                const int k0 = w * 64;
                #pragma unroll 8
                for (int kk = 0; kk < 64; ++kk) {
                    const int k = k0 + kk;
                    const float4 wv = ((const float4*)dW1)[(size_t)k * 48 + lane];
                    const float4 sv = *(const float4*)&s_s[k][0];
                    const float sr[4] = {sv.x, sv.y, sv.z, sv.w};
                    const float wc[4] = {wv.x, wv.y, wv.z, wv.w};
                    #pragma unroll
                    for (int r = 0; r < 4; ++r)
                        #pragma unroll
                        for (int c = 0; c < 4; ++c)
                            a[r][c] = fmaf(sr[r], wc[c], a[r][c]);
                }
                #pragma unroll
                for (int c = 0; c < 4; ++c)
                    *(float4*)&hp[w][4 * lane + c][0] =
                        make_float4(a[0][c], a[1][c], a[2][c], a[3][c]);
            }
            __syncthreads();

            if (tid < DM) {
                const float4 p0 = *(const float4*)&hp[0][tid][0];
                const float4 p1 = *(const float4*)&hp[1][tid][0];
                const float4 p2 = *(const float4*)&hp[2][tid][0];
                const float4 p3 = *(const float4*)&hp[3][tid][0];
                const float bb = db1[tid];
                *(float4*)&t_s[tid][0] = make_float4(
                    tanhf(p0.x + p1.x + p2.x + p3.x + bb),
                    tanhf(p0.y + p1.y + p2.y + p3.y + bb),
                    tanhf(p0.z + p1.z + p2.z + p3.z + bb),
                    tanhf(p0.w + p1.w + p2.w + p3.w + bb));
            }
            __syncthreads();   // hp reads done; safe to alias as op

            // GEMV2: wave w covers k in [48w, 48w+48); lane<32 owns cols 4lane..4lane+3
            if (lane < 32) {
                float o[4][4];
                #pragma unroll
                for (int r = 0; r < 4; ++r)
                    #pragma unroll
                    for (int c = 0; c < 4; ++c) o[r][c] = 0.f;
                const int k1 = w * 48;
                #pragma unroll 8
                for (int kk = 0; kk < 48; ++kk) {
                    const int k = k1 + kk;
                    const float4 wv = ((const float4*)dW2)[(size_t)k * 32 + lane];
                    const float4 tv = *(const float4*)&t_s[k][0];
                    const float tr[4] = {tv.x, tv.y, tv.z, tv.w};
                    const float wc[4] = {wv.x, wv.y, wv.z, wv.w};
                    #pragma unroll
                    for (int r = 0; r < 4; ++r)
                        #pragma unroll
                        for (int c = 0; c < 4; ++c)
                            o[r][c] = fmaf(tr[r], wc[c], o[r][c]);
                }
                #pragma unroll
                for (int c = 0; c < 4; ++c)
                    *(float4*)&op[w][4 * lane + c][0] =
                        make_float4(o[0][c], o[1][c], o[2][c], o[3][c]);
            }
            __syncthreads();

            if (tid < DIM) {
                const float4 q0 = *(const float4*)&op[0][tid][0];
                const float4 q1 = *(const float4*)&op[1][tid][0];
                const float4 q2 = *(const float4*)&op[2][tid][0];
                const float4 q3 = *(const float4*)&op[3][tid][0];
                const float bb = db2[tid];
                const float ov[4] = {q0.x + q1.x + q2.x + q3.x + bb,
                                     q0.y + q1.y + q2.y + q3.y + bb,
                                     q0.z + q1.z + q2.z + q3.z + bb,
                                     q0.w + q1.w + q2.w + q3.w + bb};
                #pragma unroll
                for (int r = 0; r < 4; ++r)
                    if (r < rcnt)
                        out0[((size_t)(b0 + bs[r]) * MAXN + js[r]) * DIM + tid] = ov[r];
            }
            __syncthreads();   // protect s_s/t_s/op (and keys_s window) before next tile
        }
    }
}

extern "C" void kernel_launch(void* const* d_in, const int* in_sizes, int n_in,
                              void* d_out, int out_size, void* d_ws, size_t ws_size,
                              hipStream_t stream)
{
    const float* z   = (const float*)d_in[0];
    const float* kW1 = (const float*)d_in[1];
    const float* kb1 = (const float*)d_in[2];
    const float* kg  = (const float*)d_in[3];
    const float* kbe = (const float*)d_in[4];
    const float* kW2 = (const float*)d_in[5];
    const float* kb2 = (const float*)d_in[6];
    const float* dW1 = (const float*)d_in[7];
    const float* db1 = (const float*)d_in[8];
    const float* dW2 = (const float*)d_in[9];
    const float* db2 = (const float*)d_in[10];
    const float* sW1 = (const float*)d_in[11];
    const float* sb1 = (const float*)d_in[12];
    const float* sg  = (const float*)d_in[13];
    const float* sbe = (const float*)d_in[14];
    const float* sW2 = (const float*)d_in[15];
    const float* sb2 = (const float*)d_in[16];

    float* out0       = (float*)d_out;                         // [B, 64, 128]
    float* out_logits = out0 + (size_t)B_SZ * MAXN * DIM;      // [B, 1]
    float* out_nf     = out_logits + B_SZ;                     // [B]

    uber_kernel<<<GRID_BLKS, 256, 0, stream>>>(
        z, kW1, kb1, kg, kbe, kW2, kb2,
        sW1, sb1, sg, sbe, sW2, sb2,
        dW1, db1, dW2, db2,
        out0, out_logits, out_nf);
}

// Round 12
// 89.574 us; speedup vs baseline: 1.2790x; 1.2268x over previous
//
#include <hip/hip_runtime.h>
#include <math.h>

#define B_SZ 8192
#define HID 256
#define DIM 128
#define MAXN 64
#define KM 160     // key_net mid
#define DM 192     // decoder mid
#define SM 128     // size_pred mid
#define LN_EPS 1e-5f

#define SP_BLOCKS 256          // sizepred blocks, 32 batches each
#define SP_BATCH 32
#define ZPAD 36                // z_s row stride (dwords)

// ---------------- Kernel 1: sizepred GEMM (blocks 0..255) + keys (256..319) ----------------
// (verified R8 kernel, unchanged)
__global__ void __launch_bounds__(256) sp_keys_kernel(
    const float* __restrict__ z,
    const float* __restrict__ kW1, const float* __restrict__ kb1,
    const float* __restrict__ kg,  const float* __restrict__ kbe,
    const float* __restrict__ kW2, const float* __restrict__ kb2,
    const float* __restrict__ sW1, const float* __restrict__ sb1,
    const float* __restrict__ sg,  const float* __restrict__ sbe,
    const float* __restrict__ sW2, const float* __restrict__ sb2,
    float* __restrict__ out_logits, float* __restrict__ out_nf,
    int* __restrict__ n_ws, float* __restrict__ keys)
{
    __shared__ float smem[HID * ZPAD];   // 36 KB
    const int blk = blockIdx.x;
    const int tid = threadIdx.x;

    if (blk >= SP_BLOCKS) {
        // ---------------- keys row j ----------------
        const int j = blk - SP_BLOCKS;
        float* red = smem;            // [256]
        float* t_s = smem + 256;      // [KM]

        float v = 0.f;
        if (tid < KM) v = kW1[j * KM + tid] + kb1[tid];

        red[tid] = (tid < KM) ? v : 0.f;
        __syncthreads();
        for (int s = 128; s > 0; s >>= 1) {
            if (tid < s) red[tid] += red[tid + s];
            __syncthreads();
        }
        const float mu = red[0] / (float)KM;
        __syncthreads();

        const float d = (tid < KM) ? (v - mu) : 0.f;
        red[tid] = d * d;
        __syncthreads();
        for (int s = 128; s > 0; s >>= 1) {
            if (tid < s) red[tid] += red[tid + s];
            __syncthreads();
        }
        const float rstd = rsqrtf(red[0] / (float)KM + LN_EPS);
        __syncthreads();

        if (tid < KM) t_s[tid] = tanhf(d * rstd * kg[tid] + kbe[tid]);
        __syncthreads();

        float acc = kb2[tid];
        #pragma unroll 4
        for (int k = 0; k < KM; ++k) acc = fmaf(t_s[k], kW2[k * HID + tid], acc);
        keys[j * HID + tid] = acc;
        return;
    }

    // ---------------- sizepred: 32 batches, H = Z @ sW1 then LN/ReLU/dot ----------------
    float (*z_s)[ZPAD] = (float(*)[ZPAD])smem;   // [256][36], z_s[k][b]
    const int b0 = blk * SP_BATCH;

    {
        const float4* z4 = (const float4*)z;
        #pragma unroll
        for (int i = 0; i < 8; ++i) {
            const int idx = tid + 256 * i;
            const int r = idx >> 6, c4 = idx & 63;
            const float4 v = z4[(size_t)(b0 + r) * 64 + c4];
            z_s[4 * c4 + 0][r] = v.x;
            z_s[4 * c4 + 1][r] = v.y;
            z_s[4 * c4 + 2][r] = v.z;
            z_s[4 * c4 + 3][r] = v.w;
        }
    }
    __syncthreads();

    const int cq = tid & 31;   // col quad: cols 4cq..4cq+3
    const int bg = tid >> 5;   // batch group: batches 4bg..4bg+3

    float acc[4][4];
    #pragma unroll
    for (int bi = 0; bi < 4; ++bi)
        #pragma unroll
        for (int ci = 0; ci < 4; ++ci) acc[bi][ci] = 0.f;

    const float4* w4p = (const float4*)sW1;
    #pragma unroll 4
    for (int k = 0; k < HID; ++k) {
        const float4 wv = w4p[k * 32 + cq];
        const float4 zb = *(const float4*)&z_s[k][bg * 4];
        const float zz[4] = {zb.x, zb.y, zb.z, zb.w};
        const float ww[4] = {wv.x, wv.y, wv.z, wv.w};
        #pragma unroll
        for (int bi = 0; bi < 4; ++bi)
            #pragma unroll
            for (int ci = 0; ci < 4; ++ci)
                acc[bi][ci] = fmaf(zz[bi], ww[ci], acc[bi][ci]);
    }

    const float4 g4v  = ((const float4*)sg)[cq];
    const float4 be4v = ((const float4*)sbe)[cq];
    const float4 w24v = ((const float4*)sW2)[cq];
    const float g4[4]  = {g4v.x, g4v.y, g4v.z, g4v.w};
    const float be4[4] = {be4v.x, be4v.y, be4v.z, be4v.w};
    const float w24[4] = {w24v.x, w24v.y, w24v.z, w24v.w};
    const float sb2v = sb2[0];
    const float b1_0 = sb1[4 * cq + 0], b1_1 = sb1[4 * cq + 1],
                b1_2 = sb1[4 * cq + 2], b1_3 = sb1[4 * cq + 3];

    #pragma unroll
    for (int bi = 0; bi < 4; ++bi) {
        float a[4] = {acc[bi][0] + b1_0, acc[bi][1] + b1_1,
                      acc[bi][2] + b1_2, acc[bi][3] + b1_3};
        float s = a[0] + a[1] + a[2] + a[3];
        #pragma unroll
        for (int off = 1; off < 32; off <<= 1) s += __shfl_xor(s, off, 64);
        const float mu = s * (1.f / (float)SM);
        float d[4], vs = 0.f;
        #pragma unroll
        for (int ci = 0; ci < 4; ++ci) { d[ci] = a[ci] - mu; vs = fmaf(d[ci], d[ci], vs); }
        #pragma unroll
        for (int off = 1; off < 32; off <<= 1) vs += __shfl_xor(vs, off, 64);
        const float rstd = rsqrtf(vs * (1.f / (float)SM) + LN_EPS);

        float p = 0.f;
        #pragma unroll
        for (int ci = 0; ci < 4; ++ci) {
            float h = fmaf(d[ci] * rstd, g4[ci], be4[ci]);
            h = fmaxf(h, 0.f);
            p = fmaf(h, w24[ci], p);
        }
        #pragma unroll
        for (int off = 1; off < 32; off <<= 1) p += __shfl_xor(p, off, 64);

        if (cq == 0) {
            const int b = b0 + bg * 4 + bi;
            const float logit = p + sb2v;
            int n = (int)rintf(logit);       // round-half-even == jnp.round
            n = min(max(n, 0), MAXN - 1);
            out_logits[b] = logit;
            out_nf[b] = (float)n;
            n_ws[b] = n;
        }
    }
}

// ---------------- Kernel 2: role-split — even blocks decode, odd blocks fill ----------------
// Both roles cover batch quad q = blk>>1. Fill writes rows j>=n, decode writes j<n:
// disjoint under the same n_ws -> race-free. Fill blocks exit immediately after
// issuing stores (max turnover on the store wall); decode blocks never block fill.
__global__ void __launch_bounds__(256) role_kernel(
    const float* __restrict__ z, const float* __restrict__ keys,
    const int* __restrict__ n_ws,
    const float* __restrict__ dW1, const float* __restrict__ db1,
    const float* __restrict__ dW2, const float* __restrict__ db2,
    float* __restrict__ out0)
{
    __shared__ __align__(16) float z_s[4][HID];        // 4 KB
    __shared__ __align__(16) float s_s[HID][4];        // 4 KB
    __shared__ __align__(16) float t_s[DM][4];         // 3 KB
    __shared__ __align__(16) float pbuf[4 * DM * 4];   // 12 KB: hp, reused as op
    __shared__ int n_s[4];
    __shared__ unsigned short rlist[4 * (MAXN - 1)];

    const int blk = blockIdx.x;
    const int tid = threadIdx.x;
    const int q  = blk >> 1;           // batch quad 0..2047
    const int b0 = q * 4;
    const float4 zf = make_float4(0.f, 0.f, 0.f, 0.f);

    if (blk & 1) {
        // ---------------- fill role: rows j >= n, then exit ----------------
        #pragma unroll
        for (int bi = 0; bi < 4; ++bi) {
            const int n = n_ws[b0 + bi];                     // wave-uniform scalar load
            float4* o4 = (float4*)(out0 + (size_t)(b0 + bi) * (MAXN * DIM)) + n * 32;
            const int cnt4 = (MAXN - n) * 32;
            for (int idx = tid; idx < cnt4; idx += 256) o4[idx] = zf;
        }
        return;
    }

    // ---------------- decode role: rows j < n (verified R8 tile) ----------------
    const int w = tid >> 6, lane = tid & 63;

    if (tid < 4) n_s[tid] = n_ws[b0 + tid];
    __syncthreads();

    const int total = n_s[0] + n_s[1] + n_s[2] + n_s[3];
    if (total == 0) return;                                  // ~33% of decode blocks work

    {
        const int r = tid >> 6, c4 = tid & 63;
        ((float4*)z_s[r])[c4] = ((const float4*)(z + (size_t)(b0 + r) * HID))[c4];
    }
    if (tid < 4) {
        int off = 0;
        for (int i = 0; i < tid; ++i) off += n_s[i];
        const int nn = n_s[tid];
        for (int j = 0; j < nn; ++j) rlist[off + j] = (unsigned short)((tid << 6) | j);
    }
    __syncthreads();

    float (*hp)[DM][4]  = (float(*)[DM][4])pbuf;    // GEMV1 partials
    float (*op)[DIM][4] = (float(*)[DIM][4])pbuf;   // GEMV2 partials (aliased)

    for (int base = 0; base < total; base += 4) {
        const int rcnt = min(4, total - base);
        int bs[4], js[4];
        #pragma unroll
        for (int r = 0; r < 4; ++r) {
            const int e = rlist[base + min(r, rcnt - 1)];
            bs[r] = e >> 6; js[r] = e & 63;
        }

        // stage s[k][r] = z[b_r][k] * keys[j_r][k]   (k == tid)
        #pragma unroll
        for (int r = 0; r < 4; ++r)
            s_s[tid][r] = z_s[bs[r]][tid] * keys[js[r] * HID + tid];
        __syncthreads();

        // GEMV1: wave w covers k in [64w, 64w+64); lane<48 owns cols 4lane..4lane+3
        if (lane < 48) {
            float a[4][4];
            #pragma unroll
            for (int r = 0; r < 4; ++r)
                #pragma unroll
                for (int c = 0; c < 4; ++c) a[r][c] = 0.f;
            const int k0 = w * 64;
            #pragma unroll 8
            for (int kk = 0; kk < 64; ++kk) {
                const int k = k0 + kk;
                const float4 wv = ((const float4*)dW1)[(size_t)k * 48 + lane];
                const float4 sv = *(const float4*)&s_s[k][0];
                const float sr[4] = {sv.x, sv.y, sv.z, sv.w};
                const float wc[4] = {wv.x, wv.y, wv.z, wv.w};
                #pragma unroll
                for (int r = 0; r < 4; ++r)
                    #pragma unroll
                    for (int c = 0; c < 4; ++c)
                        a[r][c] = fmaf(sr[r], wc[c], a[r][c]);
            }
            #pragma unroll
            for (int c = 0; c < 4; ++c)
                *(float4*)&hp[w][4 * lane + c][0] =
                    make_float4(a[0][c], a[1][c], a[2][c], a[3][c]);
        }
        __syncthreads();

        if (tid < DM) {
            const float4 p0 = *(const float4*)&hp[0][tid][0];
            const float4 p1 = *(const float4*)&hp[1][tid][0];
            const float4 p2 = *(const float4*)&hp[2][tid][0];
            const float4 p3 = *(const float4*)&hp[3][tid][0];
            const float bb = db1[tid];
            *(float4*)&t_s[tid][0] = make_float4(
                tanhf(p0.x + p1.x + p2.x + p3.x + bb),
                tanhf(p0.y + p1.y + p2.y + p3.y + bb),
                tanhf(p0.z + p1.z + p2.z + p3.z + bb),
                tanhf(p0.w + p1.w + p2.w + p3.w + bb));
        }
        __syncthreads();   // hp reads done; safe to alias as op

        // GEMV2: wave w covers k in [48w, 48w+48); lane<32 owns cols 4lane..4lane+3
        if (lane < 32) {
            float o[4][4];
            #pragma unroll
            for (int r = 0; r < 4; ++r)
                #pragma unroll
                for (int c = 0; c < 4; ++c) o[r][c] = 0.f;
            const int k1 = w * 48;
            #pragma unroll 8
            for (int kk = 0; kk < 48; ++kk) {
                const int k = k1 + kk;
                const float4 wv = ((const float4*)dW2)[(size_t)k * 32 + lane];
                const float4 tv = *(const float4*)&t_s[k][0];
                const float tr[4] = {tv.x, tv.y, tv.z, tv.w};
                const float wc[4] = {wv.x, wv.y, wv.z, wv.w};
                #pragma unroll
                for (int r = 0; r < 4; ++r)
                    #pragma unroll
                    for (int c = 0; c < 4; ++c)
                        o[r][c] = fmaf(tr[r], wc[c], o[r][c]);
            }
            #pragma unroll
            for (int c = 0; c < 4; ++c)
                *(float4*)&op[w][4 * lane + c][0] =
                    make_float4(o[0][c], o[1][c], o[2][c], o[3][c]);
        }
        __syncthreads();

        if (tid < DIM) {
            const float4 q0 = *(const float4*)&op[0][tid][0];
            const float4 q1 = *(const float4*)&op[1][tid][0];
            const float4 q2 = *(const float4*)&op[2][tid][0];
            const float4 q3 = *(const float4*)&op[3][tid][0];
            const float bb = db2[tid];
            const float ov[4] = {q0.x + q1.x + q2.x + q3.x + bb,
                                 q0.y + q1.y + q2.y + q3.y + bb,
                                 q0.z + q1.z + q2.z + q3.z + bb,
                                 q0.w + q1.w + q2.w + q3.w + bb};
            #pragma unroll
            for (int r = 0; r < 4; ++r)
                if (r < rcnt)
                    out0[((size_t)(b0 + bs[r]) * MAXN + js[r]) * DIM + tid] = ov[r];
        }
        __syncthreads();   // protect s_s/t_s/op before next tile
    }
}

extern "C" void kernel_launch(void* const* d_in, const int* in_sizes, int n_in,
                              void* d_out, int out_size, void* d_ws, size_t ws_size,
                              hipStream_t stream)
{
    const float* z   = (const float*)d_in[0];
    const float* kW1 = (const float*)d_in[1];
    const float* kb1 = (const float*)d_in[2];
    const float* kg  = (const float*)d_in[3];
    const float* kbe = (const float*)d_in[4];
    const float* kW2 = (const float*)d_in[5];
    const float* kb2 = (const float*)d_in[6];
    const float* dW1 = (const float*)d_in[7];
    const float* db1 = (const float*)d_in[8];
    const float* dW2 = (const float*)d_in[9];
    const float* db2 = (const float*)d_in[10];
    const float* sW1 = (const float*)d_in[11];
    const float* sb1 = (const float*)d_in[12];
    const float* sg  = (const float*)d_in[13];
    const float* sbe = (const float*)d_in[14];
    const float* sW2 = (const float*)d_in[15];
    const float* sb2 = (const float*)d_in[16];

    float* out0       = (float*)d_out;                         // [B, 64, 128]
    float* out_logits = out0 + (size_t)B_SZ * MAXN * DIM;      // [B, 1]
    float* out_nf     = out_logits + B_SZ;                     // [B]

    float* keys = (float*)d_ws;                                // 64 KB
    int*   n_ws = (int*)((char*)d_ws + 65536);                 // 32 KB

    sp_keys_kernel<<<SP_BLOCKS + MAXN, 256, 0, stream>>>(
        z, kW1, kb1, kg, kbe, kW2, kb2,
        sW1, sb1, sg, sbe, sW2, sb2,
        out_logits, out_nf, n_ws, keys);

    role_kernel<<<B_SZ / 2, 256, 0, stream>>>(
        z, keys, n_ws, dW1, db1, dW2, db2, out0);
}

// Round 13
// 82.012 us; speedup vs baseline: 1.3970x; 1.0922x over previous
//
#include <hip/hip_runtime.h>
#include <math.h>

#define B_SZ 8192
#define HID 256
#define DIM 128
#define MAXN 64
#define KM 160     // key_net mid
#define DM 192     // decoder mid
#define SM 128     // size_pred mid
#define LN_EPS 1e-5f

#define SP_BLOCKS 256          // sizepred blocks, 32 batches each
#define SP_BATCH 32
#define ZPAD 36                // z_s row stride (dwords)

// ---------------- Kernel 1: sizepred GEMM (blocks 0..255) + keys (256..319) ----------------
// (verified R8 kernel, unchanged)
__global__ void __launch_bounds__(256) sp_keys_kernel(
    const float* __restrict__ z,
    const float* __restrict__ kW1, const float* __restrict__ kb1,
    const float* __restrict__ kg,  const float* __restrict__ kbe,
    const float* __restrict__ kW2, const float* __restrict__ kb2,
    const float* __restrict__ sW1, const float* __restrict__ sb1,
    const float* __restrict__ sg,  const float* __restrict__ sbe,
    const float* __restrict__ sW2, const float* __restrict__ sb2,
    float* __restrict__ out_logits, float* __restrict__ out_nf,
    int* __restrict__ n_ws, float* __restrict__ keys)
{
    __shared__ float smem[HID * ZPAD];   // 36 KB
    const int blk = blockIdx.x;
    const int tid = threadIdx.x;

    if (blk >= SP_BLOCKS) {
        // ---------------- keys row j ----------------
        const int j = blk - SP_BLOCKS;
        float* red = smem;            // [256]
        float* t_s = smem + 256;      // [KM]

        float v = 0.f;
        if (tid < KM) v = kW1[j * KM + tid] + kb1[tid];

        red[tid] = (tid < KM) ? v : 0.f;
        __syncthreads();
        for (int s = 128; s > 0; s >>= 1) {
            if (tid < s) red[tid] += red[tid + s];
            __syncthreads();
        }
        const float mu = red[0] / (float)KM;
        __syncthreads();

        const float d = (tid < KM) ? (v - mu) : 0.f;
        red[tid] = d * d;
        __syncthreads();
        for (int s = 128; s > 0; s >>= 1) {
            if (tid < s) red[tid] += red[tid + s];
            __syncthreads();
        }
        const float rstd = rsqrtf(red[0] / (float)KM + LN_EPS);
        __syncthreads();

        if (tid < KM) t_s[tid] = tanhf(d * rstd * kg[tid] + kbe[tid]);
        __syncthreads();

        float acc = kb2[tid];
        #pragma unroll 4
        for (int k = 0; k < KM; ++k) acc = fmaf(t_s[k], kW2[k * HID + tid], acc);
        keys[j * HID + tid] = acc;
        return;
    }

    // ---------------- sizepred: 32 batches, H = Z @ sW1 then LN/ReLU/dot ----------------
    float (*z_s)[ZPAD] = (float(*)[ZPAD])smem;   // [256][36], z_s[k][b]
    const int b0 = blk * SP_BATCH;

    {
        const float4* z4 = (const float4*)z;
        #pragma unroll
        for (int i = 0; i < 8; ++i) {
            const int idx = tid + 256 * i;
            const int r = idx >> 6, c4 = idx & 63;
            const float4 v = z4[(size_t)(b0 + r) * 64 + c4];
            z_s[4 * c4 + 0][r] = v.x;
            z_s[4 * c4 + 1][r] = v.y;
            z_s[4 * c4 + 2][r] = v.z;
            z_s[4 * c4 + 3][r] = v.w;
        }
    }
    __syncthreads();

    const int cq = tid & 31;   // col quad: cols 4cq..4cq+3
    const int bg = tid >> 5;   // batch group: batches 4bg..4bg+3

    float acc[4][4];
    #pragma unroll
    for (int bi = 0; bi < 4; ++bi)
        #pragma unroll
        for (int ci = 0; ci < 4; ++ci) acc[bi][ci] = 0.f;

    const float4* w4p = (const float4*)sW1;
    #pragma unroll 4
    for (int k = 0; k < HID; ++k) {
        const float4 wv = w4p[k * 32 + cq];
        const float4 zb = *(const float4*)&z_s[k][bg * 4];
        const float zz[4] = {zb.x, zb.y, zb.z, zb.w};
        const float ww[4] = {wv.x, wv.y, wv.z, wv.w};
        #pragma unroll
        for (int bi = 0; bi < 4; ++bi)
            #pragma unroll
            for (int ci = 0; ci < 4; ++ci)
                acc[bi][ci] = fmaf(zz[bi], ww[ci], acc[bi][ci]);
    }

    const float4 g4v  = ((const float4*)sg)[cq];
    const float4 be4v = ((const float4*)sbe)[cq];
    const float4 w24v = ((const float4*)sW2)[cq];
    const float g4[4]  = {g4v.x, g4v.y, g4v.z, g4v.w};
    const float be4[4] = {be4v.x, be4v.y, be4v.z, be4v.w};
    const float w24[4] = {w24v.x, w24v.y, w24v.z, w24v.w};
    const float sb2v = sb2[0];
    const float b1_0 = sb1[4 * cq + 0], b1_1 = sb1[4 * cq + 1],
                b1_2 = sb1[4 * cq + 2], b1_3 = sb1[4 * cq + 3];

    #pragma unroll
    for (int bi = 0; bi < 4; ++bi) {
        float a[4] = {acc[bi][0] + b1_0, acc[bi][1] + b1_1,
                      acc[bi][2] + b1_2, acc[bi][3] + b1_3};
        float s = a[0] + a[1] + a[2] + a[3];
        #pragma unroll
        for (int off = 1; off < 32; off <<= 1) s += __shfl_xor(s, off, 64);
        const float mu = s * (1.f / (float)SM);
        float d[4], vs = 0.f;
        #pragma unroll
        for (int ci = 0; ci < 4; ++ci) { d[ci] = a[ci] - mu; vs = fmaf(d[ci], d[ci], vs); }
        #pragma unroll
        for (int off = 1; off < 32; off <<= 1) vs += __shfl_xor(vs, off, 64);
        const float rstd = rsqrtf(vs * (1.f / (float)SM) + LN_EPS);

        float p = 0.f;
        #pragma unroll
        for (int ci = 0; ci < 4; ++ci) {
            float h = fmaf(d[ci] * rstd, g4[ci], be4[ci]);
            h = fmaxf(h, 0.f);
            p = fmaf(h, w24[ci], p);
        }
        #pragma unroll
        for (int off = 1; off < 32; off <<= 1) p += __shfl_xor(p, off, 64);

        if (cq == 0) {
            const int b = b0 + bg * 4 + bi;
            const float logit = p + sb2v;
            int n = (int)rintf(logit);       // round-half-even == jnp.round
            n = min(max(n, 0), MAXN - 1);
            out_logits[b] = logit;
            out_nf[b] = (float)n;
            n_ws[b] = n;
        }
    }
}

// ---------------- Kernel 2: mega — decode(j<n) FIRST, fill(j>=n) LAST, 4 batches/block ----
// Valid and invalid rows are disjoint -> no ordering needed between decode and fill
// stores. Fill is issued at the block tail with NO trailing barrier, so its stores
// are never drained by a vmcnt(0) on the critical path (they retire as the block exits).
__global__ void __launch_bounds__(256) mega_kernel(
    const float* __restrict__ z, const float* __restrict__ keys,
    const int* __restrict__ n_ws,
    const float* __restrict__ dW1, const float* __restrict__ db1,
    const float* __restrict__ dW2, const float* __restrict__ db2,
    float* __restrict__ out0)
{
    __shared__ __align__(16) float z_s[4][HID];        // 4 KB
    __shared__ __align__(16) float s_s[HID][4];        // 4 KB
    __shared__ __align__(16) float t_s[DM][4];         // 3 KB
    __shared__ __align__(16) float pbuf[4 * DM * 4];   // 12 KB: hp, reused as op
    __shared__ int n_s[4];
    __shared__ unsigned short rlist[4 * (MAXN - 1)];

    const int blk = blockIdx.x;
    const int tid = threadIdx.x;
    const int w = tid >> 6, lane = tid & 63;
    const int b0 = blk * 4;

    if (tid < 4) n_s[tid] = n_ws[b0 + tid];
    __syncthreads();

    const int total = n_s[0] + n_s[1] + n_s[2] + n_s[3];

    if (total > 0) {
        // ---- stage z rows + build block-local row list ----
        {
            const int r = tid >> 6, c4 = tid & 63;
            ((float4*)z_s[r])[c4] = ((const float4*)(z + (size_t)(b0 + r) * HID))[c4];
        }
        if (tid < 4) {
            int off = 0;
            for (int i = 0; i < tid; ++i) off += n_s[i];
            const int nn = n_s[tid];
            for (int j = 0; j < nn; ++j) rlist[off + j] = (unsigned short)((tid << 6) | j);
        }
        __syncthreads();

        float (*hp)[DM][4]  = (float(*)[DM][4])pbuf;    // GEMV1 partials
        float (*op)[DIM][4] = (float(*)[DIM][4])pbuf;   // GEMV2 partials (aliased)

        // ---- decode valid rows, 4 per iteration (verified R8 tile) ----
        for (int base = 0; base < total; base += 4) {
            const int rcnt = min(4, total - base);
            int bs[4], js[4];
            #pragma unroll
            for (int r = 0; r < 4; ++r) {
                const int e = rlist[base + min(r, rcnt - 1)];
                bs[r] = e >> 6; js[r] = e & 63;
            }

            // stage s[k][r] = z[b_r][k] * keys[j_r][k]   (k == tid)
            #pragma unroll
            for (int r = 0; r < 4; ++r)
                s_s[tid][r] = z_s[bs[r]][tid] * keys[js[r] * HID + tid];
            __syncthreads();

            // GEMV1: wave w covers k in [64w, 64w+64); lane<48 owns cols 4lane..4lane+3
            if (lane < 48) {
                float a[4][4];
                #pragma unroll
                for (int r = 0; r < 4; ++r)
                    #pragma unroll
                    for (int c = 0; c < 4; ++c) a[r][c] = 0.f;
                const int k0 = w * 64;
                #pragma unroll 8
                for (int kk = 0; kk < 64; ++kk) {
                    const int k = k0 + kk;
                    const float4 wv = ((const float4*)dW1)[(size_t)k * 48 + lane];
                    const float4 sv = *(const float4*)&s_s[k][0];
                    const float sr[4] = {sv.x, sv.y, sv.z, sv.w};
                    const float wc[4] = {wv.x, wv.y, wv.z, wv.w};
                    #pragma unroll
                    for (int r = 0; r < 4; ++r)
                        #pragma unroll
                        for (int c = 0; c < 4; ++c)
                            a[r][c] = fmaf(sr[r], wc[c], a[r][c]);
                }
                #pragma unroll
                for (int c = 0; c < 4; ++c)
                    *(float4*)&hp[w][4 * lane + c][0] =
                        make_float4(a[0][c], a[1][c], a[2][c], a[3][c]);
            }
            __syncthreads();

            if (tid < DM) {
                const float4 p0 = *(const float4*)&hp[0][tid][0];
                const float4 p1 = *(const float4*)&hp[1][tid][0];
                const float4 p2 = *(const float4*)&hp[2][tid][0];
                const float4 p3 = *(const float4*)&hp[3][tid][0];
                const float bb = db1[tid];
                *(float4*)&t_s[tid][0] = make_float4(
                    tanhf(p0.x + p1.x + p2.x + p3.x + bb),
                    tanhf(p0.y + p1.y + p2.y + p3.y + bb),
                    tanhf(p0.z + p1.z + p2.z + p3.z + bb),
                    tanhf(p0.w + p1.w + p2.w + p3.w + bb));
            }
            __syncthreads();   // hp reads done; safe to alias as op

            // GEMV2: wave w covers k in [48w, 48w+48); lane<32 owns cols 4lane..4lane+3
            if (lane < 32) {
                float o[4][4];
                #pragma unroll
                for (int r = 0; r < 4; ++r)
                    #pragma unroll
                    for (int c = 0; c < 4; ++c) o[r][c] = 0.f;
                const int k1 = w * 48;
                #pragma unroll 8
                for (int kk = 0; kk < 48; ++kk) {
                    const int k = k1 + kk;
                    const float4 wv = ((const float4*)dW2)[(size_t)k * 32 + lane];
                    const float4 tv = *(const float4*)&t_s[k][0];
                    const float tr[4] = {tv.x, tv.y, tv.z, tv.w};
                    const float wc[4] = {wv.x, wv.y, wv.z, wv.w};
                    #pragma unroll
                    for (int r = 0; r < 4; ++r)
                        #pragma unroll
                        for (int c = 0; c < 4; ++c)
                            o[r][c] = fmaf(tr[r], wc[c], o[r][c]);
                }
                #pragma unroll
                for (int c = 0; c < 4; ++c)
                    *(float4*)&op[w][4 * lane + c][0] =
                        make_float4(o[0][c], o[1][c], o[2][c], o[3][c]);
            }
            __syncthreads();

            if (tid < DIM) {
                const float4 q0 = *(const float4*)&op[0][tid][0];
                const float4 q1 = *(const float4*)&op[1][tid][0];
                const float4 q2 = *(const float4*)&op[2][tid][0];
                const float4 q3 = *(const float4*)&op[3][tid][0];
                const float bb = db2[tid];
                const float ov[4] = {q0.x + q1.x + q2.x + q3.x + bb,
                                     q0.y + q1.y + q2.y + q3.y + bb,
                                     q0.z + q1.z + q2.z + q3.z + bb,
                                     q0.w + q1.w + q2.w + q3.w + bb};
                #pragma unroll
                for (int r = 0; r < 4; ++r)
                    if (r < rcnt)
                        out0[((size_t)(b0 + bs[r]) * MAXN + js[r]) * DIM + tid] = ov[r];
            }
            __syncthreads();   // protect s_s/t_s/op before next tile
        }
    }

    // ---- fill invalid rows j >= n LAST (disjoint addresses; no trailing barrier) ----
    {
        const float4 zf = make_float4(0.f, 0.f, 0.f, 0.f);
        #pragma unroll
        for (int bi = 0; bi < 4; ++bi) {
            const int n = n_s[bi];
            float4* o4 = (float4*)(out0 + (size_t)(b0 + bi) * (MAXN * DIM)) + n * 32;
            const int cnt4 = (MAXN - n) * 32;
            for (int idx = tid; idx < cnt4; idx += 256) o4[idx] = zf;
        }
    }
}

extern "C" void kernel_launch(void* const* d_in, const int* in_sizes, int n_in,
                              void* d_out, int out_size, void* d_ws, size_t ws_size,
                              hipStream_t stream)
{
    const float* z   = (const float*)d_in[0];
    const float* kW1 = (const float*)d_in[1];
    const float* kb1 = (const float*)d_in[2];
    const float* kg  = (const float*)d_in[3];
    const float* kbe = (const float*)d_in[4];
    const float* kW2 = (const float*)d_in[5];
    const float* kb2 = (const float*)d_in[6];
    const float* dW1 = (const float*)d_in[7];
    const float* db1 = (const float*)d_in[8];
    const float* dW2 = (const float*)d_in[9];
    const float* db2 = (const float*)d_in[10];
    const float* sW1 = (const float*)d_in[11];
    const float* sb1 = (const float*)d_in[12];
    const float* sg  = (const float*)d_in[13];
    const float* sbe = (const float*)d_in[14];
    const float* sW2 = (const float*)d_in[15];
    const float* sb2 = (const float*)d_in[16];

    float* out0       = (float*)d_out;                         // [B, 64, 128]
    float* out_logits = out0 + (size_t)B_SZ * MAXN * DIM;      // [B, 1]
    float* out_nf     = out_logits + B_SZ;                     // [B]

    float* keys = (float*)d_ws;                                // 64 KB
    int*   n_ws = (int*)((char*)d_ws + 65536);                 // 32 KB

    sp_keys_kernel<<<SP_BLOCKS + MAXN, 256, 0, stream>>>(
        z, kW1, kb1, kg, kbe, kW2, kb2,
        sW1, sb1, sg, sbe, sW2, sb2,
        out_logits, out_nf, n_ws, keys);

    mega_kernel<<<B_SZ / 4, 256, 0, stream>>>(
        z, keys, n_ws, dW1, db1, dW2, db2, out0);
}

// Round 15
// 81.349 us; speedup vs baseline: 1.4084x; 1.0082x over previous
//
#include <hip/hip_runtime.h>
#include <math.h>

#define B_SZ 8192
#define HID 256
#define DIM 128
#define MAXN 64
#define KM 160     // key_net mid
#define DM 192     // decoder mid
#define SM 128     // size_pred mid
#define LN_EPS 1e-5f

#define SP_BLOCKS 256          // sizepred blocks, 32 batches each
#define SP_BATCH 32
#define ZPAD 36                // z_s row stride (dwords)

typedef float floatx4 __attribute__((ext_vector_type(4)));   // native vector for nt-store

// ---------------- Kernel 1: sizepred GEMM (blocks 0..255) + keys (256..319) ----------------
// (verified R8 kernel, unchanged)
__global__ void __launch_bounds__(256) sp_keys_kernel(
    const float* __restrict__ z,
    const float* __restrict__ kW1, const float* __restrict__ kb1,
    const float* __restrict__ kg,  const float* __restrict__ kbe,
    const float* __restrict__ kW2, const float* __restrict__ kb2,
    const float* __restrict__ sW1, const float* __restrict__ sb1,
    const float* __restrict__ sg,  const float* __restrict__ sbe,
    const float* __restrict__ sW2, const float* __restrict__ sb2,
    float* __restrict__ out_logits, float* __restrict__ out_nf,
    int* __restrict__ n_ws, float* __restrict__ keys)
{
    __shared__ float smem[HID * ZPAD];   // 36 KB
    const int blk = blockIdx.x;
    const int tid = threadIdx.x;

    if (blk >= SP_BLOCKS) {
        // ---------------- keys row j ----------------
        const int j = blk - SP_BLOCKS;
        float* red = smem;            // [256]
        float* t_s = smem + 256;      // [KM]

        float v = 0.f;
        if (tid < KM) v = kW1[j * KM + tid] + kb1[tid];

        red[tid] = (tid < KM) ? v : 0.f;
        __syncthreads();
        for (int s = 128; s > 0; s >>= 1) {
            if (tid < s) red[tid] += red[tid + s];
            __syncthreads();
        }
        const float mu = red[0] / (float)KM;
        __syncthreads();

        const float d = (tid < KM) ? (v - mu) : 0.f;
        red[tid] = d * d;
        __syncthreads();
        for (int s = 128; s > 0; s >>= 1) {
            if (tid < s) red[tid] += red[tid + s];
            __syncthreads();
        }
        const float rstd = rsqrtf(red[0] / (float)KM + LN_EPS);
        __syncthreads();

        if (tid < KM) t_s[tid] = tanhf(d * rstd * kg[tid] + kbe[tid]);
        __syncthreads();

        float acc = kb2[tid];
        #pragma unroll 4
        for (int k = 0; k < KM; ++k) acc = fmaf(t_s[k], kW2[k * HID + tid], acc);
        keys[j * HID + tid] = acc;
        return;
    }

    // ---------------- sizepred: 32 batches, H = Z @ sW1 then LN/ReLU/dot ----------------
    float (*z_s)[ZPAD] = (float(*)[ZPAD])smem;   // [256][36], z_s[k][b]
    const int b0 = blk * SP_BATCH;

    {
        const float4* z4 = (const float4*)z;
        #pragma unroll
        for (int i = 0; i < 8; ++i) {
            const int idx = tid + 256 * i;
            const int r = idx >> 6, c4 = idx & 63;
            const float4 v = z4[(size_t)(b0 + r) * 64 + c4];
            z_s[4 * c4 + 0][r] = v.x;
            z_s[4 * c4 + 1][r] = v.y;
            z_s[4 * c4 + 2][r] = v.z;
            z_s[4 * c4 + 3][r] = v.w;
        }
    }
    __syncthreads();

    const int cq = tid & 31;   // col quad: cols 4cq..4cq+3
    const int bg = tid >> 5;   // batch group: batches 4bg..4bg+3

    float acc[4][4];
    #pragma unroll
    for (int bi = 0; bi < 4; ++bi)
        #pragma unroll
        for (int ci = 0; ci < 4; ++ci) acc[bi][ci] = 0.f;

    const float4* w4p = (const float4*)sW1;
    #pragma unroll 4
    for (int k = 0; k < HID; ++k) {
        const float4 wv = w4p[k * 32 + cq];
        const float4 zb = *(const float4*)&z_s[k][bg * 4];
        const float zz[4] = {zb.x, zb.y, zb.z, zb.w};
        const float ww[4] = {wv.x, wv.y, wv.z, wv.w};
        #pragma unroll
        for (int bi = 0; bi < 4; ++bi)
            #pragma unroll
            for (int ci = 0; ci < 4; ++ci)
                acc[bi][ci] = fmaf(zz[bi], ww[ci], acc[bi][ci]);
    }

    const float4 g4v  = ((const float4*)sg)[cq];
    const float4 be4v = ((const float4*)sbe)[cq];
    const float4 w24v = ((const float4*)sW2)[cq];
    const float g4[4]  = {g4v.x, g4v.y, g4v.z, g4v.w};
    const float be4[4] = {be4v.x, be4v.y, be4v.z, be4v.w};
    const float w24[4] = {w24v.x, w24v.y, w24v.z, w24v.w};
    const float sb2v = sb2[0];
    const float b1_0 = sb1[4 * cq + 0], b1_1 = sb1[4 * cq + 1],
                b1_2 = sb1[4 * cq + 2], b1_3 = sb1[4 * cq + 3];

    #pragma unroll
    for (int bi = 0; bi < 4; ++bi) {
        float a[4] = {acc[bi][0] + b1_0, acc[bi][1] + b1_1,
                      acc[bi][2] + b1_2, acc[bi][3] + b1_3};
        float s = a[0] + a[1] + a[2] + a[3];
        #pragma unroll
        for (int off = 1; off < 32; off <<= 1) s += __shfl_xor(s, off, 64);
        const float mu = s * (1.f / (float)SM);
        float d[4], vs = 0.f;
        #pragma unroll
        for (int ci = 0; ci < 4; ++ci) { d[ci] = a[ci] - mu; vs = fmaf(d[ci], d[ci], vs); }
        #pragma unroll
        for (int off = 1; off < 32; off <<= 1) vs += __shfl_xor(vs, off, 64);
        const float rstd = rsqrtf(vs * (1.f / (float)SM) + LN_EPS);

        float p = 0.f;
        #pragma unroll
        for (int ci = 0; ci < 4; ++ci) {
            float h = fmaf(d[ci] * rstd, g4[ci], be4[ci]);
            h = fmaxf(h, 0.f);
            p = fmaf(h, w24[ci], p);
        }
        #pragma unroll
        for (int off = 1; off < 32; off <<= 1) p += __shfl_xor(p, off, 64);

        if (cq == 0) {
            const int b = b0 + bg * 4 + bi;
            const float logit = p + sb2v;
            int n = (int)rintf(logit);       // round-half-even == jnp.round
            n = min(max(n, 0), MAXN - 1);
            out_logits[b] = logit;
            out_nf[b] = (float)n;
            n_ws[b] = n;
        }
    }
}

// ---------------- Kernel 2: mega — decode(j<n) FIRST, fill(j>=n) LAST (nontemporal) ----------
// Valid and invalid rows are disjoint -> no ordering needed between decode and fill
// stores. Fill uses nontemporal stores: streams past L2, keeping dW1/dW2/keys L2-hot
// for the decode blocks and avoiding read/write L2 contention.
__global__ void __launch_bounds__(256) mega_kernel(
    const float* __restrict__ z, const float* __restrict__ keys,
    const int* __restrict__ n_ws,
    const float* __restrict__ dW1, const float* __restrict__ db1,
    const float* __restrict__ dW2, const float* __restrict__ db2,
    float* __restrict__ out0)
{
    __shared__ __align__(16) float z_s[4][HID];        // 4 KB
    __shared__ __align__(16) float s_s[HID][4];        // 4 KB
    __shared__ __align__(16) float t_s[DM][4];         // 3 KB
    __shared__ __align__(16) float pbuf[4 * DM * 4];   // 12 KB: hp, reused as op
    __shared__ int n_s[4];
    __shared__ unsigned short rlist[4 * (MAXN - 1)];

    const int blk = blockIdx.x;
    const int tid = threadIdx.x;
    const int w = tid >> 6, lane = tid & 63;
    const int b0 = blk * 4;

    if (tid < 4) n_s[tid] = n_ws[b0 + tid];
    __syncthreads();

    const int total = n_s[0] + n_s[1] + n_s[2] + n_s[3];

    if (total > 0) {
        // ---- stage z rows + build block-local row list ----
        {
            const int r = tid >> 6, c4 = tid & 63;
            ((float4*)z_s[r])[c4] = ((const float4*)(z + (size_t)(b0 + r) * HID))[c4];
        }
        if (tid < 4) {
            int off = 0;
            for (int i = 0; i < tid; ++i) off += n_s[i];
            const int nn = n_s[tid];
            for (int j = 0; j < nn; ++j) rlist[off + j] = (unsigned short)((tid << 6) | j);
        }
        __syncthreads();

        float (*hp)[DM][4]  = (float(*)[DM][4])pbuf;    // GEMV1 partials
        float (*op)[DIM][4] = (float(*)[DIM][4])pbuf;   // GEMV2 partials (aliased)

        // ---- decode valid rows, 4 per iteration (verified R8 tile) ----
        for (int base = 0; base < total; base += 4) {
            const int rcnt = min(4, total - base);
            int bs[4], js[4];
            #pragma unroll
            for (int r = 0; r < 4; ++r) {
                const int e = rlist[base + min(r, rcnt - 1)];
                bs[r] = e >> 6; js[r] = e & 63;
            }

            // stage s[k][r] = z[b_r][k] * keys[j_r][k]   (k == tid)
            #pragma unroll
            for (int r = 0; r < 4; ++r)
                s_s[tid][r] = z_s[bs[r]][tid] * keys[js[r] * HID + tid];
            __syncthreads();

            // GEMV1: wave w covers k in [64w, 64w+64); lane<48 owns cols 4lane..4lane+3
            if (lane < 48) {
                float a[4][4];
                #pragma unroll
                for (int r = 0; r < 4; ++r)
                    #pragma unroll
                    for (int c = 0; c < 4; ++c) a[r][c] = 0.f;
                const int k0 = w * 64;
                #pragma unroll 8
                for (int kk = 0; kk < 64; ++kk) {
                    const int k = k0 + kk;
                    const float4 wv = ((const float4*)dW1)[(size_t)k * 48 + lane];
                    const float4 sv = *(const float4*)&s_s[k][0];
                    const float sr[4] = {sv.x, sv.y, sv.z, sv.w};
                    const float wc[4] = {wv.x, wv.y, wv.z, wv.w};
                    #pragma unroll
                    for (int r = 0; r < 4; ++r)
                        #pragma unroll
                        for (int c = 0; c < 4; ++c)
                            a[r][c] = fmaf(sr[r], wc[c], a[r][c]);
                }
                #pragma unroll
                for (int c = 0; c < 4; ++c)
                    *(float4*)&hp[w][4 * lane + c][0] =
                        make_float4(a[0][c], a[1][c], a[2][c], a[3][c]);
            }
            __syncthreads();

            if (tid < DM) {
                const float4 p0 = *(const float4*)&hp[0][tid][0];
                const float4 p1 = *(const float4*)&hp[1][tid][0];
                const float4 p2 = *(const float4*)&hp[2][tid][0];
                const float4 p3 = *(const float4*)&hp[3][tid][0];
                const float bb = db1[tid];
                *(float4*)&t_s[tid][0] = make_float4(
                    tanhf(p0.x + p1.x + p2.x + p3.x + bb),
                    tanhf(p0.y + p1.y + p2.y + p3.y + bb),
                    tanhf(p0.z + p1.z + p2.z + p3.z + bb),
                    tanhf(p0.w + p1.w + p2.w + p3.w + bb));
            }
            __syncthreads();   // hp reads done; safe to alias as op

            // GEMV2: wave w covers k in [48w, 48w+48); lane<32 owns cols 4lane..4lane+3
            if (lane < 32) {
                float o[4][4];
                #pragma unroll
                for (int r = 0; r < 4; ++r)
                    #pragma unroll
                    for (int c = 0; c < 4; ++c) o[r][c] = 0.f;
                const int k1 = w * 48;
                #pragma unroll 8
                for (int kk = 0; kk < 48; ++kk) {
                    const int k = k1 + kk;
                    const float4 wv = ((const float4*)dW2)[(size_t)k * 32 + lane];
                    const float4 tv = *(const float4*)&t_s[k][0];
                    const float tr[4] = {tv.x, tv.y, tv.z, tv.w};
                    const float wc[4] = {wv.x, wv.y, wv.z, wv.w};
                    #pragma unroll
                    for (int r = 0; r < 4; ++r)
                        #pragma unroll
                        for (int c = 0; c < 4; ++c)
                            o[r][c] = fmaf(tr[r], wc[c], o[r][c]);
                }
                #pragma unroll
                for (int c = 0; c < 4; ++c)
                    *(float4*)&op[w][4 * lane + c][0] =
                        make_float4(o[0][c], o[1][c], o[2][c], o[3][c]);
            }
            __syncthreads();

            if (tid < DIM) {
                const float4 q0 = *(const float4*)&op[0][tid][0];
                const float4 q1 = *(const float4*)&op[1][tid][0];
                const float4 q2 = *(const float4*)&op[2][tid][0];
                const float4 q3 = *(const float4*)&op[3][tid][0];
                const float bb = db2[tid];
                const float ov[4] = {q0.x + q1.x + q2.x + q3.x + bb,
                                     q0.y + q1.y + q2.y + q3.y + bb,
                                     q0.z + q1.z + q2.z + q3.z + bb,
                                     q0.w + q1.w + q2.w + q3.w + bb};
                #pragma unroll
                for (int r = 0; r < 4; ++r)
                    if (r < rcnt)
                        out0[((size_t)(b0 + bs[r]) * MAXN + js[r]) * DIM + tid] = ov[r];
            }
            __syncthreads();   // protect s_s/t_s/op before next tile
        }
    }

    // ---- fill invalid rows j >= n LAST (nontemporal streaming stores, no barrier) ----
    {
        const floatx4 zf = {0.f, 0.f, 0.f, 0.f};
        #pragma unroll
        for (int bi = 0; bi < 4; ++bi) {
            const int n = n_s[bi];
            floatx4* o4 = (floatx4*)(out0 + (size_t)(b0 + bi) * (MAXN * DIM)) + n * 32;
            const int cnt4 = (MAXN - n) * 32;
            for (int idx = tid; idx < cnt4; idx += 256)
                __builtin_nontemporal_store(zf, &o4[idx]);
        }
    }
}

extern "C" void kernel_launch(void* const* d_in, const int* in_sizes, int n_in,
                              void* d_out, int out_size, void* d_ws, size_t ws_size,
                              hipStream_t stream)
{
    const float* z   = (const float*)d_in[0];
    const float* kW1 = (const float*)d_in[1];
    const float* kb1 = (const float*)d_in[2];
    const float* kg  = (const float*)d_in[3];
    const float* kbe = (const float*)d_in[4];
    const float* kW2 = (const float*)d_in[5];
    const float* kb2 = (const float*)d_in[6];
    const float* dW1 = (const float*)d_in[7];
    const float* db1 = (const float*)d_in[8];
    const float* dW2 = (const float*)d_in[9];
    const float* db2 = (const float*)d_in[10];
    const float* sW1 = (const float*)d_in[11];
    const float* sb1 = (const float*)d_in[12];
    const float* sg  = (const float*)d_in[13];
    const float* sbe = (const float*)d_in[14];
    const float* sW2 = (const float*)d_in[15];
    const float* sb2 = (const float*)d_in[16];

    float* out0       = (float*)d_out;                         // [B, 64, 128]
    float* out_logits = out0 + (size_t)B_SZ * MAXN * DIM;      // [B, 1]
    float* out_nf     = out_logits + B_SZ;                     // [B]

    float* keys = (float*)d_ws;                                // 64 KB
    int*   n_ws = (int*)((char*)d_ws + 65536);                 // 32 KB

    sp_keys_kernel<<<SP_BLOCKS + MAXN, 256, 0, stream>>>(
        z, kW1, kb1, kg, kbe, kW2, kb2,
        sW1, sb1, sg, sbe, sW2, sb2,
        out_logits, out_nf, n_ws, keys);

    mega_kernel<<<B_SZ / 4, 256, 0, stream>>>(
        z, keys, n_ws, dW1, db1, dW2, db2, out0);
}

// Round 16
// 80.356 us; speedup vs baseline: 1.4258x; 1.0124x over previous
//
#include <hip/hip_runtime.h>
#include <math.h>

#define B_SZ 8192
#define HID 256
#define DIM 128
#define MAXN 64
#define KM 160     // key_net mid
#define DM 192     // decoder mid
#define SM 128     // size_pred mid
#define LN_EPS 1e-5f

#define SP_BLOCKS 256          // sizepred blocks, 32 batches each
#define SP_BATCH 32
#define ZPAD 36                // z_s row stride (dwords)

typedef float floatx4 __attribute__((ext_vector_type(4)));   // native vector for nt-store

// ---------------- Kernel 1: sizepred GEMM (blocks 0..255) + keys (256..319) ----------------
// (verified R8 kernel, unchanged)
__global__ void __launch_bounds__(256) sp_keys_kernel(
    const float* __restrict__ z,
    const float* __restrict__ kW1, const float* __restrict__ kb1,
    const float* __restrict__ kg,  const float* __restrict__ kbe,
    const float* __restrict__ kW2, const float* __restrict__ kb2,
    const float* __restrict__ sW1, const float* __restrict__ sb1,
    const float* __restrict__ sg,  const float* __restrict__ sbe,
    const float* __restrict__ sW2, const float* __restrict__ sb2,
    float* __restrict__ out_logits, float* __restrict__ out_nf,
    int* __restrict__ n_ws, float* __restrict__ keys)
{
    __shared__ float smem[HID * ZPAD];   // 36 KB
    const int blk = blockIdx.x;
    const int tid = threadIdx.x;

    if (blk >= SP_BLOCKS) {
        // ---------------- keys row j ----------------
        const int j = blk - SP_BLOCKS;
        float* red = smem;            // [256]
        float* t_s = smem + 256;      // [KM]

        float v = 0.f;
        if (tid < KM) v = kW1[j * KM + tid] + kb1[tid];

        red[tid] = (tid < KM) ? v : 0.f;
        __syncthreads();
        for (int s = 128; s > 0; s >>= 1) {
            if (tid < s) red[tid] += red[tid + s];
            __syncthreads();
        }
        const float mu = red[0] / (float)KM;
        __syncthreads();

        const float d = (tid < KM) ? (v - mu) : 0.f;
        red[tid] = d * d;
        __syncthreads();
        for (int s = 128; s > 0; s >>= 1) {
            if (tid < s) red[tid] += red[tid + s];
            __syncthreads();
        }
        const float rstd = rsqrtf(red[0] / (float)KM + LN_EPS);
        __syncthreads();

        if (tid < KM) t_s[tid] = tanhf(d * rstd * kg[tid] + kbe[tid]);
        __syncthreads();

        float acc = kb2[tid];
        #pragma unroll 4
        for (int k = 0; k < KM; ++k) acc = fmaf(t_s[k], kW2[k * HID + tid], acc);
        keys[j * HID + tid] = acc;
        return;
    }

    // ---------------- sizepred: 32 batches, H = Z @ sW1 then LN/ReLU/dot ----------------
    float (*z_s)[ZPAD] = (float(*)[ZPAD])smem;   // [256][36], z_s[k][b]
    const int b0 = blk * SP_BATCH;

    {
        const float4* z4 = (const float4*)z;
        #pragma unroll
        for (int i = 0; i < 8; ++i) {
            const int idx = tid + 256 * i;
            const int r = idx >> 6, c4 = idx & 63;
            const float4 v = z4[(size_t)(b0 + r) * 64 + c4];
            z_s[4 * c4 + 0][r] = v.x;
            z_s[4 * c4 + 1][r] = v.y;
            z_s[4 * c4 + 2][r] = v.z;
            z_s[4 * c4 + 3][r] = v.w;
        }
    }
    __syncthreads();

    const int cq = tid & 31;   // col quad: cols 4cq..4cq+3
    const int bg = tid >> 5;   // batch group: batches 4bg..4bg+3

    float acc[4][4];
    #pragma unroll
    for (int bi = 0; bi < 4; ++bi)
        #pragma unroll
        for (int ci = 0; ci < 4; ++ci) acc[bi][ci] = 0.f;

    const float4* w4p = (const float4*)sW1;
    #pragma unroll 4
    for (int k = 0; k < HID; ++k) {
        const float4 wv = w4p[k * 32 + cq];
        const float4 zb = *(const float4*)&z_s[k][bg * 4];
        const float zz[4] = {zb.x, zb.y, zb.z, zb.w};
        const float ww[4] = {wv.x, wv.y, wv.z, wv.w};
        #pragma unroll
        for (int bi = 0; bi < 4; ++bi)
            #pragma unroll
            for (int ci = 0; ci < 4; ++ci)
                acc[bi][ci] = fmaf(zz[bi], ww[ci], acc[bi][ci]);
    }

    const float4 g4v  = ((const float4*)sg)[cq];
    const float4 be4v = ((const float4*)sbe)[cq];
    const float4 w24v = ((const float4*)sW2)[cq];
    const float g4[4]  = {g4v.x, g4v.y, g4v.z, g4v.w};
    const float be4[4] = {be4v.x, be4v.y, be4v.z, be4v.w};
    const float w24[4] = {w24v.x, w24v.y, w24v.z, w24v.w};
    const float sb2v = sb2[0];
    const float b1_0 = sb1[4 * cq + 0], b1_1 = sb1[4 * cq + 1],
                b1_2 = sb1[4 * cq + 2], b1_3 = sb1[4 * cq + 3];

    #pragma unroll
    for (int bi = 0; bi < 4; ++bi) {
        float a[4] = {acc[bi][0] + b1_0, acc[bi][1] + b1_1,
                      acc[bi][2] + b1_2, acc[bi][3] + b1_3};
        float s = a[0] + a[1] + a[2] + a[3];
        #pragma unroll
        for (int off = 1; off < 32; off <<= 1) s += __shfl_xor(s, off, 64);
        const float mu = s * (1.f / (float)SM);
        float d[4], vs = 0.f;
        #pragma unroll
        for (int ci = 0; ci < 4; ++ci) { d[ci] = a[ci] - mu; vs = fmaf(d[ci], d[ci], vs); }
        #pragma unroll
        for (int off = 1; off < 32; off <<= 1) vs += __shfl_xor(vs, off, 64);
        const float rstd = rsqrtf(vs * (1.f / (float)SM) + LN_EPS);

        float p = 0.f;
        #pragma unroll
        for (int ci = 0; ci < 4; ++ci) {
            float h = fmaf(d[ci] * rstd, g4[ci], be4[ci]);
            h = fmaxf(h, 0.f);
            p = fmaf(h, w24[ci], p);
        }
        #pragma unroll
        for (int off = 1; off < 32; off <<= 1) p += __shfl_xor(p, off, 64);

        if (cq == 0) {
            const int b = b0 + bg * 4 + bi;
            const float logit = p + sb2v;
            int n = (int)rintf(logit);       // round-half-even == jnp.round
            n = min(max(n, 0), MAXN - 1);
            out_logits[b] = logit;
            out_nf[b] = (float)n;
            n_ws[b] = n;
        }
    }
}

// ---------------- Kernel 2: mega — decode(j<n) FIRST, fill(j>=n) LAST (nontemporal) ----------
// n loaded as wave-uniform scalar loads (no LDS round-trip / no leading barrier).
// Fast path for total==0 (76% of blocks): fully unrolled contiguous 128KB NT fill.
__global__ void __launch_bounds__(256) mega_kernel(
    const float* __restrict__ z, const float* __restrict__ keys,
    const int* __restrict__ n_ws,
    const float* __restrict__ dW1, const float* __restrict__ db1,
    const float* __restrict__ dW2, const float* __restrict__ db2,
    float* __restrict__ out0)
{
    __shared__ __align__(16) float z_s[4][HID];        // 4 KB
    __shared__ __align__(16) float s_s[HID][4];        // 4 KB
    __shared__ __align__(16) float t_s[DM][4];         // 3 KB
    __shared__ __align__(16) float pbuf[4 * DM * 4];   // 12 KB: hp, reused as op
    __shared__ unsigned short rlist[4 * (MAXN - 1)];

    const int blk = blockIdx.x;
    const int tid = threadIdx.x;
    const int w = tid >> 6, lane = tid & 63;
    const int b0 = blk * 4;

    // wave-uniform scalar loads of n (s_load; no LDS, no barrier)
    const int nn0 = n_ws[b0 + 0];
    const int nn1 = n_ws[b0 + 1];
    const int nn2 = n_ws[b0 + 2];
    const int nn3 = n_ws[b0 + 3];
    const int nn[4] = {nn0, nn1, nn2, nn3};
    const int total = nn0 + nn1 + nn2 + nn3;
    const floatx4 zf = {0.f, 0.f, 0.f, 0.f};

    if (total == 0) {
        // ---- fast path: contiguous 128 KB branchless NT fill (harness-fill shape) ----
        floatx4* o4 = (floatx4*)(out0 + (size_t)b0 * (MAXN * DIM));
        #pragma unroll
        for (int i = 0; i < 32; ++i)
            __builtin_nontemporal_store(zf, &o4[i * 256 + tid]);
        return;
    }

    // ---- stage z rows + build block-local row list ----
    {
        const int r = tid >> 6, c4 = tid & 63;
        ((float4*)z_s[r])[c4] = ((const float4*)(z + (size_t)(b0 + r) * HID))[c4];
    }
    if (tid < 4) {
        int off = 0;
        for (int i = 0; i < tid; ++i) off += nn[i];
        const int cnt = nn[tid];
        for (int j = 0; j < cnt; ++j) rlist[off + j] = (unsigned short)((tid << 6) | j);
    }
    __syncthreads();

    float (*hp)[DM][4]  = (float(*)[DM][4])pbuf;    // GEMV1 partials
    float (*op)[DIM][4] = (float(*)[DIM][4])pbuf;   // GEMV2 partials (aliased)

    // ---- decode valid rows, 4 per iteration (verified R8 tile) ----
    for (int base = 0; base < total; base += 4) {
        const int rcnt = min(4, total - base);
        int bs[4], js[4];
        #pragma unroll
        for (int r = 0; r < 4; ++r) {
            const int e = rlist[base + min(r, rcnt - 1)];
            bs[r] = e >> 6; js[r] = e & 63;
        }

        // stage s[k][r] = z[b_r][k] * keys[j_r][k]   (k == tid)
        #pragma unroll
        for (int r = 0; r < 4; ++r)
            s_s[tid][r] = z_s[bs[r]][tid] * keys[js[r] * HID + tid];
        __syncthreads();

        // GEMV1: wave w covers k in [64w, 64w+64); lane<48 owns cols 4lane..4lane+3
        if (lane < 48) {
            float a[4][4];
            #pragma unroll
            for (int r = 0; r < 4; ++r)
                #pragma unroll
                for (int c = 0; c < 4; ++c) a[r][c] = 0.f;
            const int k0 = w * 64;
            #pragma unroll 8
            for (int kk = 0; kk < 64; ++kk) {
                const int k = k0 + kk;
                const float4 wv = ((const float4*)dW1)[(size_t)k * 48 + lane];
                const float4 sv = *(const float4*)&s_s[k][0];
                const float sr[4] = {sv.x, sv.y, sv.z, sv.w};
                const float wc[4] = {wv.x, wv.y, wv.z, wv.w};
                #pragma unroll
                for (int r = 0; r < 4; ++r)
                    #pragma unroll
                    for (int c = 0; c < 4; ++c)
                        a[r][c] = fmaf(sr[r], wc[c], a[r][c]);
            }
            #pragma unroll
            for (int c = 0; c < 4; ++c)
                *(float4*)&hp[w][4 * lane + c][0] =
                    make_float4(a[0][c], a[1][c], a[2][c], a[3][c]);
        }
        __syncthreads();

        if (tid < DM) {
            const float4 p0 = *(const float4*)&hp[0][tid][0];
            const float4 p1 = *(const float4*)&hp[1][tid][0];
            const float4 p2 = *(const float4*)&hp[2][tid][0];
            const float4 p3 = *(const float4*)&hp[3][tid][0];
            const float bb = db1[tid];
            *(float4*)&t_s[tid][0] = make_float4(
                tanhf(p0.x + p1.x + p2.x + p3.x + bb),
                tanhf(p0.y + p1.y + p2.y + p3.y + bb),
                tanhf(p0.z + p1.z + p2.z + p3.z + bb),
                tanhf(p0.w + p1.w + p2.w + p3.w + bb));
        }
        __syncthreads();   // hp reads done; safe to alias as op

        // GEMV2: wave w covers k in [48w, 48w+48); lane<32 owns cols 4lane..4lane+3
        if (lane < 32) {
            float o[4][4];
            #pragma unroll
            for (int r = 0; r < 4; ++r)
                #pragma unroll
                for (int c = 0; c < 4; ++c) o[r][c] = 0.f;
            const int k1 = w * 48;
            #pragma unroll 8
            for (int kk = 0; kk < 48; ++kk) {
                const int k = k1 + kk;
                const float4 wv = ((const float4*)dW2)[(size_t)k * 32 + lane];
                const float4 tv = *(const float4*)&t_s[k][0];
                const float tr[4] = {tv.x, tv.y, tv.z, tv.w};
                const float wc[4] = {wv.x, wv.y, wv.z, wv.w};
                #pragma unroll
                for (int r = 0; r < 4; ++r)
                    #pragma unroll
                    for (int c = 0; c < 4; ++c)
                        o[r][c] = fmaf(tr[r], wc[c], o[r][c]);
            }
            #pragma unroll
            for (int c = 0; c < 4; ++c)
                *(float4*)&op[w][4 * lane + c][0] =
                    make_float4(o[0][c], o[1][c], o[2][c], o[3][c]);
        }
        __syncthreads();

        if (tid < DIM) {
            const float4 q0 = *(const float4*)&op[0][tid][0];
            const float4 q1 = *(const float4*)&op[1][tid][0];
            const float4 q2 = *(const float4*)&op[2][tid][0];
            const float4 q3 = *(const float4*)&op[3][tid][0];
            const float bb = db2[tid];
            const float ov[4] = {q0.x + q1.x + q2.x + q3.x + bb,
                                 q0.y + q1.y + q2.y + q3.y + bb,
                                 q0.z + q1.z + q2.z + q3.z + bb,
                                 q0.w + q1.w + q2.w + q3.w + bb};
            #pragma unroll
            for (int r = 0; r < 4; ++r)
                if (r < rcnt)
                    out0[((size_t)(b0 + bs[r]) * MAXN + js[r]) * DIM + tid] = ov[r];
        }
        __syncthreads();   // protect s_s/t_s/op before next tile
    }

    // ---- fill invalid rows j >= n LAST (nontemporal streaming stores, no barrier) ----
    #pragma unroll
    for (int bi = 0; bi < 4; ++bi) {
        const int n = nn[bi];
        floatx4* o4 = (floatx4*)(out0 + (size_t)(b0 + bi) * (MAXN * DIM)) + n * 32;
        const int cnt4 = (MAXN - n) * 32;
        for (int idx = tid; idx < cnt4; idx += 256)
            __builtin_nontemporal_store(zf, &o4[idx]);
    }
}

extern "C" void kernel_launch(void* const* d_in, const int* in_sizes, int n_in,
                              void* d_out, int out_size, void* d_ws, size_t ws_size,
                              hipStream_t stream)
{
    const float* z   = (const float*)d_in[0];
    const float* kW1 = (const float*)d_in[1];
    const float* kb1 = (const float*)d_in[2];
    const float* kg  = (const float*)d_in[3];
    const float* kbe = (const float*)d_in[4];
    const float* kW2 = (const float*)d_in[5];
    const float* kb2 = (const float*)d_in[6];
    const float* dW1 = (const float*)d_in[7];
    const float* db1 = (const float*)d_in[8];
    const float* dW2 = (const float*)d_in[9];
    const float* db2 = (const float*)d_in[10];
    const float* sW1 = (const float*)d_in[11];
    const float* sb1 = (const float*)d_in[12];
    const float* sg  = (const float*)d_in[13];
    const float* sbe = (const float*)d_in[14];
    const float* sW2 = (const float*)d_in[15];
    const float* sb2 = (const float*)d_in[16];

    float* out0       = (float*)d_out;                         // [B, 64, 128]
    float* out_logits = out0 + (size_t)B_SZ * MAXN * DIM;      // [B, 1]
    float* out_nf     = out_logits + B_SZ;                     // [B]

    float* keys = (float*)d_ws;                                // 64 KB
    int*   n_ws = (int*)((char*)d_ws + 65536);                 // 32 KB

    sp_keys_kernel<<<SP_BLOCKS + MAXN, 256, 0, stream>>>(
        z, kW1, kb1, kg, kbe, kW2, kb2,
        sW1, sb1, sg, sbe, sW2, sb2,
        out_logits, out_nf, n_ws, keys);

    mega_kernel<<<B_SZ / 4, 256, 0, stream>>>(
        z, keys, n_ws, dW1, db1, dW2, db2, out0);
}